// Round 2
// baseline (358.601 us; speedup 1.0000x reference)
//
#include <hip/hip_runtime.h>

// Problem constants (from reference): B=16, S=4096, H=768, NUM_WORDS=2048.
constexpr int B = 16;
constexpr int S = 4096;
constexpr int H = 768;
constexpr int NW = 2048;
constexpr int V4 = H / 4;           // 192 float4 per token row
constexpr int WPW = 8;              // words per wave (streaming group)
constexpr int WAVES_PER_BLK = 4;    // 256-thread blocks
constexpr int GPS = NW / WPW;       // 256 word-groups per sample
constexpr int D = 6;                // token pipeline depth (18 float4 in flight)

// Phase 1: word_ids[b, 1..S-2] is non-decreasing (increments 0/1), sentinels
// -1 at s=0, s=S-1. Position s starts word row[s] iff row[s] != row[s-1].
__global__ __launch_bounds__(256)
void find_starts_kernel(const int* __restrict__ wid, int* __restrict__ starts) {
    const int idx = blockIdx.x * 256 + threadIdx.x; // over B*S
    const int s = idx & (S - 1);
    const int b = idx >> 12;
    if (s < 1 || s >= S - 1) return;
    const int* __restrict__ row = wid + (size_t)b * S;
    const int cur = row[s];
    if (cur != row[s - 1] && cur >= 0) starts[b * NW + cur] = s;
}

__device__ __forceinline__ void acc4(float4& a, const float4 v) {
    a.x += v.x; a.y += v.y; a.z += v.z; a.w += v.w;
}

// Phase 2: one WAVE per 8 consecutive words. The group's tokens form ONE
// contiguous range [s_begin, s_end); a depth-D register ring buffer keeps
// D tokens (3*D float4 loads) in flight ACROSS word boundaries. Word
// flushes are wave-uniform branches; stores are always younger than any
// load being waited on, so no store-drain stalls.
__global__ __launch_bounds__(64 * WAVES_PER_BLK, 4)
void seg_mean_kernel(const float* __restrict__ hs,
                     const int* __restrict__ wid,
                     const int* __restrict__ starts,
                     float* __restrict__ out) {
    const int wave = threadIdx.x >> 6;
    const int lane = threadIdx.x & 63;
    const int gw = blockIdx.x * WAVES_PER_BLK + wave;  // global wave id
    const int b = gw >> 8;                             // / GPS
    const int w0 = (gw & (GPS - 1)) * WPW;
    const int base_blk = b * NW + w0;

    // One lane-parallel gather for all wave-uniform control data.
    int ctrl;
    if (lane <= WPW) {
        const int i = base_blk + lane;
        ctrl = (i < B * NW) ? starts[i] : (S - 1);
    } else if (lane == WPW + 1) {
        ctrl = wid[(size_t)b * S + (S - 2)];           // maxw for this sample
    } else {
        ctrl = 0;
    }
    const int maxw = __builtin_amdgcn_readlane(ctrl, WPW + 1);

    float4* __restrict__ obase = (float4*)(out + (size_t)base_blk * H);
    const float4 z = make_float4(0.f, 0.f, 0.f, 0.f);

    if (w0 > maxw) {  // whole group nonexistent -> zeros
#pragma unroll
        for (int i = 0; i < WPW; ++i) {
            float4* o = obase + (size_t)i * V4;
            o[lane] = z; o[lane + 64] = z; o[lane + 128] = z;
        }
        return;
    }

    const int nw_exist = min(WPW, maxw - w0 + 1);      // >= 1
    const int last_w = w0 + nw_exist - 1;
    const int s_begin = __builtin_amdgcn_readlane(ctrl, 0);
    const int s_end = (last_w == maxw)
                          ? (S - 1)
                          : __builtin_amdgcn_readlane(ctrl, nw_exist);

    const float4* __restrict__ base = (const float4*)(hs + (size_t)b * S * H);

    // --- software pipeline: register ring buffer of D tokens ---
    float4 r0[D], r1[D], r2[D];
#pragma unroll
    for (int j = 0; j < D; ++j) {
        int t = s_begin + j;
        t = (t < s_end) ? t : (s_end - 1);             // clamped (harmless)
        const float4* p = base + (size_t)t * V4;
        r0[j] = p[lane]; r1[j] = p[lane + 64]; r2[j] = p[lane + 128];
    }

    int widx = 0;                                      // word index in group
    int cur_start = s_begin;
    int cur_end = (w0 == maxw) ? (S - 1) : __builtin_amdgcn_readlane(ctrl, 1);
    float4 a0 = z, a1 = z, a2 = z;
    int t = s_begin;                                   // next token to consume
    int tload = s_begin + D;                           // next token to load

    while (t < s_end) {
#pragma unroll
        for (int j = 0; j < D; ++j) {
            if (t < s_end) {
                // consume slot j (compiler emits counted vmcnt wait)
                acc4(a0, r0[j]); acc4(a1, r1[j]); acc4(a2, r2[j]);
                // refill slot j with token t+D (clamped)
                int tl = (tload < s_end) ? tload : (s_end - 1);
                const float4* p = base + (size_t)tl * V4;
                r0[j] = p[lane]; r1[j] = p[lane + 64]; r2[j] = p[lane + 128];
                ++tload;
                ++t;
                if (t == cur_end) {                    // flush word widx
                    const float inv = 1.0f / (float)(cur_end - cur_start);
                    float4 m0 = a0, m1 = a1, m2 = a2;
                    m0.x *= inv; m0.y *= inv; m0.z *= inv; m0.w *= inv;
                    m1.x *= inv; m1.y *= inv; m1.z *= inv; m1.w *= inv;
                    m2.x *= inv; m2.y *= inv; m2.z *= inv; m2.w *= inv;
                    float4* o = obase + (size_t)widx * V4;
                    o[lane] = m0; o[lane + 64] = m1; o[lane + 128] = m2;
                    a0 = z; a1 = z; a2 = z;
                    ++widx;
                    cur_start = cur_end;
                    const int w = w0 + widx;
                    cur_end = (w >= maxw) ? (S - 1)
                                          : __builtin_amdgcn_readlane(ctrl, widx + 1);
                }
            }
        }
    }

    // zero-fill nonexistent tail words of the group
    for (int i = nw_exist; i < WPW; ++i) {
        float4* o = obase + (size_t)i * V4;
        o[lane] = z; o[lane + 64] = z; o[lane + 128] = z;
    }
}

extern "C" void kernel_launch(void* const* d_in, const int* in_sizes, int n_in,
                              void* d_out, int out_size, void* d_ws, size_t ws_size,
                              hipStream_t stream) {
    const float* hs = (const float*)d_in[0];
    const int* wid = (const int*)d_in[1];
    float* out = (float*)d_out;
    int* starts = (int*)d_ws;  // B*NW ints = 128 KB scratch

    find_starts_kernel<<<(B * S) / 256, 256, 0, stream>>>(wid, starts);
    seg_mean_kernel<<<(B * GPS) / WAVES_PER_BLK, 64 * WAVES_PER_BLK, 0, stream>>>(
        hs, wid, starts, out);
}

// Round 3
// 309.834 us; speedup vs baseline: 1.1574x; 1.1574x over previous
//
#include <hip/hip_runtime.h>

// Problem constants (from reference): B=16, S=4096, H=768, NUM_WORDS=2048.
constexpr int B = 16;
constexpr int S = 4096;
constexpr int H = 768;
constexpr int NW = 2048;
constexpr int V4 = H / 4;               // 192 float4 per token row
constexpr int W = 8;                    // tokens per wave window
constexpr int WPS = 512;                // windows per sample (4094 tokens / 8, padded)
constexpr int WAVES_PER_BLK = 4;

__device__ __forceinline__ void acc4(float4& a, const float4 v) {
    a.x += v.x; a.y += v.y; a.z += v.z; a.w += v.w;
}

// One wave owns the 8-token window [t0, t0+8) and ALL words STARTING in it
// (reading past the window end for the rare crossing word). All 24 window
// loads are issued back-to-back into named registers, pinned above a
// sched_barrier so the compiler cannot serialize them. Word boundaries come
// from one 64-lane wid gather + ballot -> wave-uniform scalar mask.
__global__ __launch_bounds__(256)
void seg_mean_kernel(const float* __restrict__ hs,
                     const int* __restrict__ wid,
                     float* __restrict__ out) {
    const int wave = threadIdx.x >> 6;
    const int lane = threadIdx.x & 63;
    const int gwin = blockIdx.x * WAVES_PER_BLK + wave;
    const int b = gwin >> 9;                 // / WPS
    const int win = gwin & (WPS - 1);
    const int t0 = 1 + win * W;              // tokens 0 and S-1 are sentinels

    const int* __restrict__ wrow = wid + (size_t)b * S;

    // wid gather FIRST (oldest outstanding -> its wait leaves token loads in
    // flight). Lanes 0..62: wid[t0-1+lane] (clamped); lane 63: maxw.
    int gidx = t0 - 1 + lane;
    if (gidx > S - 1) gidx = S - 1;
    if (lane == 63) gidx = S - 2;
    const int wv = wrow[gidx];

    // 24 token-row loads, individually named, issued back-to-back.
    const float4* __restrict__ base = (const float4*)(hs + (size_t)b * S * H);
#define TOKS(X) X(0) X(1) X(2) X(3) X(4) X(5) X(6) X(7)
#define DECL(J) float4 rA##J, rB##J, rC##J;
    TOKS(DECL)
#define LOADTOK(J) { int t = t0 + J; if (t > S - 2) t = S - 2;              \
        const float4* p = base + (size_t)t * V4;                           \
        rA##J = p[lane]; rB##J = p[lane + 64]; rC##J = p[lane + 128]; }
    TOKS(LOADTOK)
    __builtin_amdgcn_sched_barrier(0);  // loads stay above, consumes below

    const int maxw = __builtin_amdgcn_readlane(wv, 63);

    // boundary mask: bit l (1..62) => token (t0-1+l) has wid != previous token
    const int wprev = __shfl_up(wv, 1);
    const bool chg = (lane >= 1) && (lane <= 62) && (wv != wprev);
    const unsigned long long mask = __ballot(chg);

    const float4 z = make_float4(0.f, 0.f, 0.f, 0.f);
    float4 a0 = z, a1 = z, a2 = z;
    int cnt = 0, wcur = 0;
    bool active = false;

    auto flush = [&]() {
        const float inv = 1.0f / (float)cnt;
        float4 m0 = a0, m1 = a1, m2 = a2;
        m0.x *= inv; m0.y *= inv; m0.z *= inv; m0.w *= inv;
        m1.x *= inv; m1.y *= inv; m1.z *= inv; m1.w *= inv;
        m2.x *= inv; m2.y *= inv; m2.z *= inv; m2.w *= inv;
        float4* o = (float4*)(out + ((size_t)b * NW + wcur) * H);
        o[lane] = m0; o[lane + 64] = m1; o[lane + 128] = m2;
    };

    // window steps: token t0+J <-> mask bit J+1 <-> wv lane J+1
#define STEP(J) {                                                          \
        if ((mask >> (J + 1)) & 1ull) {                                    \
            if (active) flush();                                           \
            const int wval = __builtin_amdgcn_readlane(wv, J + 1);         \
            active = (wval >= 0);                                          \
            if (active) { wcur = wval; a0 = z; a1 = z; a2 = z; cnt = 0; }  \
        }                                                                  \
        if (active) { acc4(a0, rA##J); acc4(a1, rB##J); acc4(a2, rC##J); ++cnt; } }
    TOKS(STEP)
#undef STEP
#undef LOADTOK
#undef DECL
#undef TOKS

    // extension: last owned word crosses the window end
    if (active) {
        int end;
        const unsigned long long hi = mask >> 9;  // bits for tokens t0+8..t0+61
        if (hi) {
            end = t0 + 8 + __builtin_ctzll(hi);
        } else {
            end = t0 + 62;  // tokens t0+8..t0+61 confirmed same word
            while (true) {  // wid is non-decreasing: first differing = word end
                int t = end + lane;
                if (t > S - 1) t = S - 1;
                const int wv2 = wrow[t];
                const unsigned long long m2 = __ballot(wv2 != wcur);
                if (m2) { end += __builtin_ctzll(m2); break; }
                end += 64;
            }
        }
        cnt += end - (t0 + 8);
        int t = t0 + 8;
        for (; t + 3 < end; t += 4) {  // 12 independent loads per iteration
            const float4* p0 = base + (size_t)t * V4;
            const float4* p1 = p0 + V4;
            const float4* p2 = p1 + V4;
            const float4* p3 = p2 + V4;
            float4 x00 = p0[lane], x01 = p0[lane + 64], x02 = p0[lane + 128];
            float4 x10 = p1[lane], x11 = p1[lane + 64], x12 = p1[lane + 128];
            float4 x20 = p2[lane], x21 = p2[lane + 64], x22 = p2[lane + 128];
            float4 x30 = p3[lane], x31 = p3[lane + 64], x32 = p3[lane + 128];
            acc4(a0, x00); acc4(a1, x01); acc4(a2, x02);
            acc4(a0, x10); acc4(a1, x11); acc4(a2, x12);
            acc4(a0, x20); acc4(a1, x21); acc4(a2, x22);
            acc4(a0, x30); acc4(a1, x31); acc4(a2, x32);
        }
        for (; t < end; ++t) {
            const float4* p = base + (size_t)t * V4;
            float4 v0 = p[lane], v1 = p[lane + 64], v2 = p[lane + 128];
            acc4(a0, v0); acc4(a1, v1); acc4(a2, v2);
        }
        flush();
    }

    // zero-duty: words w > maxw are never produced -> write zero rows.
    // 512 windows x 4 words cover all 2048 word slots of this sample.
    {
        const int wz0 = win * 4;
#pragma unroll
        for (int k = 0; k < 4; ++k) {
            const int w = wz0 + k;
            if (w > maxw) {
                float4* o = (float4*)(out + ((size_t)b * NW + w) * H);
                o[lane] = z; o[lane + 64] = z; o[lane + 128] = z;
            }
        }
    }
}

extern "C" void kernel_launch(void* const* d_in, const int* in_sizes, int n_in,
                              void* d_out, int out_size, void* d_ws, size_t ws_size,
                              hipStream_t stream) {
    const float* hs = (const float*)d_in[0];
    const int* wid = (const int*)d_in[1];
    float* out = (float*)d_out;

    seg_mean_kernel<<<(B * WPS) / WAVES_PER_BLK, 64 * WAVES_PER_BLK, 0, stream>>>(
        hs, wid, out);
}